// Round 2
// baseline (101.799 us; speedup 1.0000x reference)
//
#include <hip/hip_runtime.h>
#include <stdint.h>
#include <stddef.h>

// Problem: out[b][o] = sum_{i,g} spline(x[b][i])[g] * coef[o][i][g]
//   x: (4096, 1024) f32; coef: (1024, 1024, 8) f32; out: (4096, 1024) f32
// == GEMM: A (4096 x 8192) * B^T (1024 x 8192), K = i*8+g.
//
// Operands pre-shuffled into 16x16x32-MFMA fragment images (prep_kernel);
// GEMM stages whole 1KB fragments via global_load_lds; every ds_read is
// base+lane*16 (conflict-free).
// R2 change: OCCUPANCY. 256x128 tile, 4 waves/block (256 thr), per-wave
// 128x64 output (128 AGPR acc), BK=32, THREE 24KiB LDS buffers (72 KiB)
// -> 2 independent blocks/CU (16 waves/CU). Cross-block async covers the
// barrier/read/vmcnt phases that serialized the old 1-block/CU schedule
// (R0/R1 both stuck at MfmaUtil 47%; intra-block reordering was null).
// Stage distance 2 steps -> steady-state counted vmcnt(6), never 0.
// Split-K 4: s=0 writes C f32; s>0 write bf16 partials; reduce sums.

#define BATCH 4096
#define IN    1024
#define OUTN  1024
#define KDIM  (IN * 8)      // 8192
#define NSTEP (KDIM / 32)   // 256 K-steps of BK=32

typedef __attribute__((ext_vector_type(8)))  short          short8;
typedef __attribute__((ext_vector_type(8)))  unsigned short ushort8;
typedef __attribute__((ext_vector_type(4)))  float          f32x4;

// ---------- helpers ----------

__device__ __forceinline__ constexpr float Cf(int i) {
    constexpr double end  = 1.0 + 2.0 * 4.0 / 7.0;        // 1 + 8/7
    constexpr double step = (end - (-1.0)) / 11.0;
    return (float)(-1.0 + (double)i * step);
}

__device__ __forceinline__ unsigned short f2bf(float f) {
    unsigned int u = __builtin_bit_cast(unsigned int, f);
    u += 0x7fffu + ((u >> 16) & 1u);      // round-to-nearest-even
    return (unsigned short)(u >> 16);
}

__device__ __forceinline__ float bf2f(unsigned short u) {
    unsigned int v = (unsigned int)u << 16;
    return __builtin_bit_cast(float, v);
}

__device__ __forceinline__ ushort8 spline8(float xt) {
    float v[11];
#pragma unroll
    for (int j = 0; j < 11; ++j)
        v[j] = (xt >= Cf(j) && xt < Cf(j + 1)) ? 1.0f : 0.0f;
#pragma unroll
    for (int k = 1; k <= 3; ++k) {
#pragma unroll
        for (int j = 0; j < 11 - k; ++j) {
            float left  = (xt - Cf(j))         * (1.0f / (Cf(j + k)     - Cf(j)));
            float right = (Cf(j + k + 1) - xt) * (1.0f / (Cf(j + k + 1) - Cf(j + 1)));
            v[j] = left * v[j] + right * v[j + 1];
        }
    }
    ushort8 r;
#pragma unroll
    for (int g = 0; g < 8; ++g) r[g] = f2bf(v[g]);
    return r;
}

typedef const unsigned int __attribute__((address_space(1))) gu32;
typedef unsigned int       __attribute__((address_space(3))) lu32;

__device__ __forceinline__ void gload_lds16(const void* g, void* l) {
    __builtin_amdgcn_global_load_lds((gu32*)g, (lu32*)l, 16, 0, 0);
}

// ---------- kernel 1: fused prep -> A_shuf / B_shuf fragment images ----------
//
// 16x16x32 frag map: row = lane&15, k = kb*32 + (lane>>4)*8 + e.
// Image (ushort8 units): [rg=row>>4][kb=k>>5][lane][e].
// Element (row, i, g): kb = i>>2, lane = (i&3)*16 + (row&15), e = g.

__global__ void prep_kernel(const float* __restrict__ x, const float* __restrict__ coef,
                            unsigned short* __restrict__ A, unsigned short* __restrict__ B) {
    const int t = threadIdx.x;
    int blk = blockIdx.x;
    if (blk < 4096) {
        // basis: 256 bb x 16 bi blocks; row = b
        const int bb = blk >> 4, bi = blk & 15;
        const int b  = bb * 16 + (t & 15);
        const int i0 = bi * 64 + (t >> 4) * 4;
        f32x4 xv = *reinterpret_cast<const f32x4*>(&x[(size_t)b * IN + i0]);
        ushort8 r[4];
#pragma unroll
        for (int j = 0; j < 4; ++j) r[j] = spline8(tanhf(xv[j]));
        ushort8* out = reinterpret_cast<ushort8*>(A)
                     + ((size_t)(bb * 256 + bi * 16 + (t >> 4)) * 64) + (t & 15);
        out[0]  = r[0];
        out[16] = r[1];
        out[32] = r[2];
        out[48] = r[3];
    } else {
        // coef cvt: 64 ob x 16 ib blocks; row = o
        blk -= 4096;
        const int ob = blk >> 4, ib = blk & 15;
        const int oo = ob * 16 + (t & 15);
        const int i0 = ib * 64 + (t >> 4) * 4;
        const f32x4* cin = reinterpret_cast<const f32x4*>(coef);
        ushort8 r[4];
#pragma unroll
        for (int j = 0; j < 4; ++j) {
            f32x4 v0 = cin[((size_t)oo * IN + i0 + j) * 2];
            f32x4 v1 = cin[((size_t)oo * IN + i0 + j) * 2 + 1];
#pragma unroll
            for (int g = 0; g < 4; ++g) { r[j][g] = f2bf(v0[g]); r[j][4 + g] = f2bf(v1[g]); }
        }
        ushort8* out = reinterpret_cast<ushort8*>(B)
                     + ((size_t)(ob * 256 + ib * 16 + (t >> 4)) * 64) + (t & 15);
        out[0]  = r[0];
        out[16] = r[1];
        out[32] = r[2];
        out[48] = r[3];
    }
}

// ---------- kernel 2: 256x128 bf16 GEMM, BK=32, 2 blocks/CU ----------
//
// 4 waves (wm=w>>1 row-half, wn=w&1 col-half), per-wave output 128x64:
// acc[8 mf][4 nf]. Per step T (buf CUR=T%3, NXT, STG=(T+2)%3):
//  P1: BAR; stage step T+2 -> STG (6 gloads); MFMA mf0..3; read aF[4..7]<-CUR
//  P2: vmcnt(6) [retires step T+1's stages, leaves T+2's 6]; BAR;
//      MFMA mf4..7; pre-read aF[0..3],bv <- NXT (step T+1)
// Slot-reuse safety: STG's last reads were consumed (lgkm-waited by MFMA)
// before the preceding barrier; pre-reads follow the vmcnt+BAR pair that
// publishes the staged data from ALL waves. Two indep blocks per CU cover
// each other's barrier/read/vmcnt stalls.

template<int NSPLIT>
__global__ __launch_bounds__(256, 2) void gemm_bt(
        const unsigned short* __restrict__ Ashuf,  // [256 rg][256 kb][64][8]
        const unsigned short* __restrict__ Bshuf,  // [64 cg][256 kb][64][8]
        float* __restrict__ C,                     // [4096][1024]
        unsigned short* __restrict__ P) {          // bf16 partials (splits 1..)
    constexpr int NT2 = NSTEP / NSPLIT;            // K-steps per block
    static_assert(NT2 >= 8 && (NT2 - 4) % 3 == 0, "tail assumes (NT2-4)%3==0");
    __shared__ unsigned short Ls[3][12288];        // 3 bufs x 24 KiB = 72 KiB

    const int tid  = threadIdx.x;
    const int w    = tid >> 6;                     // 0..3
    const int lane = tid & 63;
    const int wm   = w >> 1, wn = w & 1;
    const int lane8 = lane * 8;
    const int w4 = w * 4, w2 = w * 2;

    const int bid  = blockIdx.x;
    const int s    = (NSPLIT == 1) ? 0 : (bid & (NSPLIT - 1));
    const int tile = (NSPLIT == 1) ? bid : (bid / NSPLIT); // 0..127
    const int tm   = tile >> 3;                    // 0..15
    const int tn   = tile & 7;                     // 0..7
    const int mb16 = tm * 16;                      // A rg base
    const int nb8  = tn * 8;                       // B cg base
    const int T0   = s * NT2;
    const int brow = tm * 256, bcol = tn * 128;

    // Per step: A 16 frags (rg 0..15), B 8 frags (cg 0..7); wave w stages
    // A rg = w*4+j (j 0..3) and B cg = w*2+j (j 0..1). 1 KiB per gload.
#define STAGE(T2, LS) do {                                                    \
        size_t _kq = (size_t)(T0 + (T2)) * 512 + lane8;                       \
        _Pragma("unroll")                                                     \
        for (int j = 0; j < 4; ++j)                                           \
            gload_lds16(Ashuf + (((size_t)(mb16 + w4 + j)) << 17) + _kq,      \
                        (LS) + (w4 + j) * 512);                               \
        _Pragma("unroll")                                                     \
        for (int j = 0; j < 2; ++j)                                           \
            gload_lds16(Bshuf + (((size_t)(nb8 + w2 + j)) << 17) + _kq,       \
                        (LS) + 8192 + (w2 + j) * 512);                        \
    } while (0)

#define LDA_LO(LS) do {                                                      \
        _Pragma("unroll")                                                    \
        for (int mf = 0; mf < 4; ++mf)                                       \
            aF[mf] = *reinterpret_cast<const short8*>(                       \
                (LS) + (wm * 8 + mf) * 512 + lane8);                         \
    } while (0)
#define LDA_HI(LS) do {                                                     \
        _Pragma("unroll")                                                    \
        for (int mf = 0; mf < 4; ++mf)                                       \
            aF[4 + mf] = *reinterpret_cast<const short8*>(                   \
                (LS) + (wm * 8 + 4 + mf) * 512 + lane8);                     \
    } while (0)
#define LDB(LS) do {                                                         \
        _Pragma("unroll")                                                    \
        for (int nf = 0; nf < 4; ++nf)                                       \
            bv[nf] = *reinterpret_cast<const short8*>(                       \
                (LS) + 8192 + (wn * 4 + nf) * 512 + lane8);                  \
    } while (0)

    f32x4 acc[8][4] = {};                          // [mf][nf]
    short8 aF[8], bv[4];

#define MFMA_HALF(L) do {                                                     \
        __builtin_amdgcn_s_setprio(1);                                        \
        _Pragma("unroll")                                                     \
        for (int mf = 0; mf < 4; ++mf)                                        \
            _Pragma("unroll")                                                 \
            for (int nf = 0; nf < 4; ++nf)                                    \
                acc[(L)*4 + mf][nf] =                                         \
                    __builtin_amdgcn_mfma_f32_16x16x32_bf16(                  \
                        aF[(L)*4 + mf], bv[nf], acc[(L)*4 + mf][nf], 0, 0, 0);\
        __builtin_amdgcn_s_setprio(0);                                        \
    } while (0)

#define STEP(T, CUR, NXT, STG, SFLAG, VC, RN) do {                            \
        __builtin_amdgcn_s_barrier();                                         \
        if (SFLAG) STAGE((T) + 2, STG);                                       \
        MFMA_HALF(0);                                                         \
        LDA_HI(CUR);                                                          \
        asm volatile("s_waitcnt vmcnt(" VC ")" ::: "memory");                 \
        __builtin_amdgcn_s_barrier();                                         \
        MFMA_HALF(1);                                                         \
        if (RN) { LDA_LO(NXT); LDB(NXT); }                                    \
    } while (0)

    unsigned short* b0 = &Ls[0][0];
    unsigned short* b1 = &Ls[1][0];
    unsigned short* b2 = &Ls[2][0];

    // prologue: prime steps 0,1; publish step 0; pre-read its lo-half.
    STAGE(0, b0);
    STAGE(1, b1);
    asm volatile("s_waitcnt vmcnt(6)" ::: "memory");
    __builtin_amdgcn_s_barrier();
    LDA_LO(b0); LDB(b0);

#pragma unroll 1
    for (int t = 0; t < NT2 - 4; t += 3) {
        STEP(t,     b0, b1, b2, 1, "6", 1);
        STEP(t + 1, b1, b2, b0, 1, "6", 1);
        STEP(t + 2, b2, b0, b1, 1, "6", 1);
    }
    STEP(NT2 - 4, b0, b1, b2, 1, "6", 1);
    STEP(NT2 - 3, b1, b2, b0, 1, "6", 1);
    STEP(NT2 - 2, b2, b0, b1, 0, "0", 1);
    STEP(NT2 - 1, b0, b1, b2, 0, "0", 0);

    // epilogue: C/D layout col=lane&15, row=(lane>>4)*4+reg (m89-verified)
    // s==0 -> f32 to C; s>0 -> bf16 partial slab (reduce kernel sums).
    const int q4 = (lane >> 4) * 4, frow = lane & 15;
    if (NSPLIT == 1 || s == 0) {
#pragma unroll
        for (int mf = 0; mf < 8; ++mf)
#pragma unroll
            for (int nf = 0; nf < 4; ++nf)
#pragma unroll
                for (int r = 0; r < 4; ++r) {
                    int row = brow + wm * 128 + mf * 16 + q4 + r;
                    int col = bcol + wn * 64 + nf * 16 + frow;
                    C[(size_t)row * OUTN + col] = acc[mf][nf][r];
                }
    } else {
        unsigned short* Pb = P + (size_t)(s - 1) * BATCH * OUTN;
#pragma unroll
        for (int mf = 0; mf < 8; ++mf)
#pragma unroll
            for (int nf = 0; nf < 4; ++nf)
#pragma unroll
                for (int r = 0; r < 4; ++r) {
                    int row = brow + wm * 128 + mf * 16 + q4 + r;
                    int col = bcol + wn * 64 + nf * 16 + frow;
                    Pb[(size_t)row * OUTN + col] = f2bf(acc[mf][nf][r]);
                }
    }
}

// ---------- kernel 3: C += sum of np bf16 partials ----------

__global__ void reduce_kernel(float* __restrict__ C, const unsigned short* __restrict__ P,
                              int np) {
    int i = blockIdx.x * 256 + threadIdx.x;        // 524,288 threads x 8 f32
    size_t base = (size_t)i * 8;
    f32x4 c0 = *reinterpret_cast<f32x4*>(&C[base]);
    f32x4 c1 = *reinterpret_cast<f32x4*>(&C[base + 4]);
    for (int j = 0; j < np; ++j) {
        ushort8 p = *reinterpret_cast<const ushort8*>(&P[(size_t)j * BATCH * OUTN + base]);
#pragma unroll
        for (int e = 0; e < 4; ++e) c0[e] += bf2f(p[e]);
#pragma unroll
        for (int e = 0; e < 4; ++e) c1[e] += bf2f(p[4 + e]);
    }
    *reinterpret_cast<f32x4*>(&C[base])     = c0;
    *reinterpret_cast<f32x4*>(&C[base + 4]) = c1;
}

// ---------- launch ----------

extern "C" void kernel_launch(void* const* d_in, const int* in_sizes, int n_in,
                              void* d_out, int out_size, void* d_ws, size_t ws_size,
                              hipStream_t stream) {
    const float* x    = (const float*)d_in[0];
    const float* coef = (const float*)d_in[1];
    float* out = (float*)d_out;

    // ws: [A_shuf 64 MiB][B_shuf 16 MiB][bf16 partials 8 MiB x (NSPLIT-1)]
    unsigned short* ashuf = (unsigned short*)d_ws;
    unsigned short* bshuf = ashuf + (size_t)BATCH * KDIM;
    unsigned short* part  = bshuf + (size_t)OUTN * KDIM;
    const size_t base = (size_t)BATCH * KDIM * 2 + (size_t)OUTN * KDIM * 2;  // 80 MiB
    const size_t slab = (size_t)BATCH * OUTN * 2;                            // 8 MiB

    prep_kernel<<<5120, 256, 0, stream>>>(x, coef, ashuf, bshuf);

    if (ws_size >= base + 3 * slab) {
        // 128 tiles x split-K 4 = 512 blocks = 2 per CU
        gemm_bt<4><<<512, 256, 0, stream>>>(ashuf, bshuf, out, part);
        reduce_kernel<<<2048, 256, 0, stream>>>(out, part, 3);
    } else {
        gemm_bt<1><<<128, 256, 0, stream>>>(ashuf, bshuf, out, nullptr);
    }
}